// Round 6
// baseline (274.180 us; speedup 1.0000x reference)
//
#include <hip/hip_runtime.h>

#define NN 100000
#define EE 1600000
#define HN 128
#define OO 64
#define SB 256     // stats blocks
#define NBUCK 196  // ceil(NN/512), bucket = row >> 9
#define CH 4096    // edges per bucketing chunk

typedef __attribute__((ext_vector_type(8))) short bf16x8;
typedef __attribute__((ext_vector_type(4))) float f32x4;

__device__ __forceinline__ unsigned short f2bf(float f){ // RNE bf16
  unsigned u = __float_as_uint(f);
  return (unsigned short)((u + 0x7FFFu + ((u >> 16) & 1u)) >> 16);
}
__device__ __forceinline__ float bflo(unsigned u){ return __uint_as_float(u << 16); }
__device__ __forceinline__ float bfhi(unsigned u){ return __uint_as_float(u & 0xFFFF0000u); }

// ---------------- CSR build: bucketed ----------------
__global__ __launch_bounds__(256) void k_hist(const int* __restrict__ rows, int* __restrict__ bcnt){
  __shared__ int h[NBUCK];
  for (int i = threadIdx.x; i < NBUCK; i += 256) h[i] = 0;
  __syncthreads();
  int base = blockIdx.x * CH;
  for (int j = threadIdx.x; j < CH; j += 256){
    int e = base + j;
    if (e < EE) atomicAdd(&h[rows[e] >> 9], 1);
  }
  __syncthreads();
  for (int i = threadIdx.x; i < NBUCK; i += 256){
    int v = h[i];
    if (v) atomicAdd(&bcnt[i], v);
  }
}

__global__ __launch_bounds__(64) void k_bscan(const int* __restrict__ bcnt,
                                              int* __restrict__ bbase, int* __restrict__ bcur){
  int lane = threadIdx.x;
  int run = 0;
  for (int c = 0; c < NBUCK; c += 64){
    int i = c + lane;
    int v = (i < NBUCK) ? bcnt[i] : 0;
    int s = v;
    #pragma unroll
    for (int d = 1; d < 64; d <<= 1){ int u = __shfl_up(s, d); if (lane >= d) s += u; }
    if (i < NBUCK){ bbase[i] = run + s - v; bcur[i] = run + s - v; }
    run += __shfl(s, 63);
  }
}

__global__ __launch_bounds__(256) void k_bucket(const int* __restrict__ rows, const int* __restrict__ cols,
                                                int* __restrict__ bcur, uint2* __restrict__ ebuf){
  __shared__ int bc[NBUCK];
  __shared__ int boff[NBUCK];
  __shared__ int ccur[NBUCK];
  __shared__ int gbase[NBUCK];
  __shared__ uint2 stage[CH];
  const int t = threadIdx.x;
  const int base = blockIdx.x * CH;
  const int nval = min(CH, EE - base);

  for (int i = t; i < NBUCK; i += 256) bc[i] = 0;
  __syncthreads();

  int er[16], ec[16];
  #pragma unroll
  for (int j = 0; j < 16; ++j){
    int i = j*256 + t;
    if (i < nval){
      er[j] = rows[base+i]; ec[j] = cols[base+i];
      atomicAdd(&bc[er[j] >> 9], 1);
    } else er[j] = -1;
  }
  __syncthreads();

  if (t < 64){
    int lane = t, run = 0;
    for (int c = 0; c < NBUCK; c += 64){
      int i = c + lane;
      int v = (i < NBUCK) ? bc[i] : 0;
      int s = v;
      #pragma unroll
      for (int d = 1; d < 64; d <<= 1){ int u = __shfl_up(s, d); if (lane >= d) s += u; }
      if (i < NBUCK) boff[i] = run + s - v;
      run += __shfl(s, 63);
    }
  }
  __syncthreads();
  if (t < NBUCK){
    gbase[t] = bc[t] ? atomicAdd(&bcur[t], bc[t]) : 0;
    ccur[t]  = boff[t];
  }
  __syncthreads();
  #pragma unroll
  for (int j = 0; j < 16; ++j){
    if (er[j] >= 0){
      int b = er[j] >> 9;
      int p = atomicAdd(&ccur[b], 1);
      stage[p] = make_uint2((unsigned)er[j], (unsigned)ec[j]);
    }
  }
  __syncthreads();
  for (int i = t; i < nval; i += 256){
    uint2 e = stage[i];
    int b = (int)(e.x >> 9);
    ebuf[gbase[b] + (i - boff[b])] = e;
  }
}

__global__ __launch_bounds__(256) void k_build(const uint2* __restrict__ ebuf,
                                               const int* __restrict__ bbase, const int* __restrict__ bcnt,
                                               int* __restrict__ row_start, int* __restrict__ cnt,
                                               float* __restrict__ dinv, int* __restrict__ csr_col){
  __shared__ int hist[512];
  __shared__ int cur[512];
  const int b = blockIdx.x;
  const int row0 = b << 9;
  const int nrow = min(512, NN - row0);
  const int ebase = bbase[b];
  const int ne = bcnt[b];
  const int t = threadIdx.x;

  for (int i = t; i < nrow; i += 256) hist[i] = 0;
  __syncthreads();
  for (int i = t; i < ne; i += 256)
    atomicAdd(&hist[(int)ebuf[ebase+i].x - row0], 1);
  __syncthreads();

  if (t < 64){
    int lane = t, run = 0;
    for (int c = 0; c < nrow; c += 64){
      int i = c + lane;
      int v = (i < nrow) ? hist[i] : 0;
      int s = v;
      #pragma unroll
      for (int d = 1; d < 64; d <<= 1){ int u = __shfl_up(s, d); if (lane >= d) s += u; }
      if (i < nrow) cur[i] = run + s - v;
      run += __shfl(s, 63);
    }
  }
  __syncthreads();
  for (int i = t; i < nrow; i += 256){
    int h = hist[i];
    int r = row0 + i;
    cnt[r] = h;
    dinv[r] = rsqrtf((float)(h+1));
    row_start[r] = ebase + cur[i];
    cur[i] += ebase;
  }
  __syncthreads();
  for (int i = t; i < ne; i += 256){
    uint2 e = ebuf[ebase+i];
    int p = atomicAdd(&cur[(int)e.x - row0], 1);
    csr_col[p] = (int)e.y;
  }
}

// ---------------- aggregation: one wave per row, 2 edges per instruction ----------------
// h rows bf16-packed (256 B). lanes 0-31 = even edge, 32-63 = odd edge; lane covers 4 features.
// out[r] = dr*(h'[r] + sum_c h'[c]) + bias
template<bool BF16OUT>
__global__ __launch_bounds__(256) void k_agg(const unsigned* __restrict__ h,
                                             const int* __restrict__ row_start,
                                             const int* __restrict__ cnt,
                                             const int* __restrict__ col,
                                             const float* __restrict__ dinv,
                                             const float* __restrict__ bias,
                                             void* __restrict__ outv){
  const int wib  = __builtin_amdgcn_readfirstlane((int)(threadIdx.x >> 6));  // SGPR wave id
  const int wid  = blockIdx.x*4 + wib;
  if (wid >= NN) return;
  const int lane = threadIdx.x & 63;
  const int half = lane >> 5;
  const int lh   = lane & 31;
  const int s = row_start[wid];       // uniform -> scalar loads
  const int n = cnt[wid];
  const float dr = dinv[wid];
  const char* hb = (const char*)h;

  float a0=0.f, a1=0.f, a2=0.f, a3=0.f;
  if (half == 0){ // self row (256 B, half-wave)
    uint2 q = *reinterpret_cast<const uint2*>(hb + (size_t)wid*256 + lh*8);
    a0 = bflo(q.x); a1 = bfhi(q.x); a2 = bflo(q.y); a3 = bfhi(q.y);
  }

  int p = 0;
  #define PAIRS(U)                                                              \
    {                                                                           \
      uint2 q[U];                                                               \
      _Pragma("unroll")                                                         \
      for (int i = 0; i < U; ++i){                                              \
        int ca = col[s + p + 2*i];                                              \
        int cb = col[s + p + 2*i + 1];                                          \
        int c  = half ? cb : ca;                                                \
        q[i] = *reinterpret_cast<const uint2*>(hb + (size_t)c*256 + lh*8);      \
      }                                                                         \
      _Pragma("unroll")                                                         \
      for (int i = 0; i < U; ++i){                                              \
        a0 += bflo(q[i].x); a1 += bfhi(q[i].x);                                 \
        a2 += bflo(q[i].y); a3 += bfhi(q[i].y);                                 \
      }                                                                         \
      p += 2*U;                                                                 \
    }

  while (p + 16 <= n) PAIRS(8)
  if (p + 8 <= n) PAIRS(4)
  if (p + 4 <= n) PAIRS(2)
  if (p + 2 <= n) PAIRS(1)
  #undef PAIRS
  if (p < n){ // odd tail: one edge, half 0 only (no wasted fetch: exec-masked)
    int c = col[s + p];
    if (half == 0){
      uint2 q = *reinterpret_cast<const uint2*>(hb + (size_t)c*256 + lh*8);
      a0 += bflo(q.x); a1 += bfhi(q.x); a2 += bflo(q.y); a3 += bfhi(q.y);
    }
  }

  // combine halves
  a0 += __shfl_xor(a0, 32);
  a1 += __shfl_xor(a1, 32);
  a2 += __shfl_xor(a2, 32);
  a3 += __shfl_xor(a3, 32);

  if (half == 0){
    float4 bb = *reinterpret_cast<const float4*>(bias + lh*4);
    float o0 = a0*dr + bb.x, o1 = a1*dr + bb.y;
    float o2 = a2*dr + bb.z, o3 = a3*dr + bb.w;
    if constexpr (BF16OUT){
      uint2 o;
      o.x = (unsigned)f2bf(o0) | ((unsigned)f2bf(o1) << 16);
      o.y = (unsigned)f2bf(o2) | ((unsigned)f2bf(o3) << 16);
      *reinterpret_cast<uint2*>((char*)outv + (size_t)wid*256 + lh*8) = o;
    } else {
      *reinterpret_cast<float4*>((float*)outv + (size_t)wid*HN + lh*4) = make_float4(o0,o1,o2,o3);
    }
  }
}

// ---------------- W pack (all 3 weights in one dispatch) ----------------
__global__ __launch_bounds__(256) void k_packW3(const float* __restrict__ W1, const float* __restrict__ W2,
                                                const float* __restrict__ W3,
                                                unsigned short* __restrict__ Wp1, unsigned short* __restrict__ Wp2,
                                                unsigned short* __restrict__ Wp3){
  int b = blockIdx.x;
  const float* W; unsigned short* Wp; int outc, i0;
  if (b < 8)      { W=W1; Wp=Wp1; outc=128; i0 = b*256; }
  else if (b < 16){ W=W2; Wp=Wp2; outc=128; i0 = (b-8)*256; }
  else            { W=W3; Wp=Wp3; outc=64;  i0 = (b-16)*256; }
  int i = i0 + threadIdx.x;
  if (i >= 16*outc) return;
  int kb = i / outc, n = i - kb*outc;
  unsigned pk[4];
  #pragma unroll
  for (int jj = 0; jj < 4; ++jj){
    unsigned lo = f2bf(W[(size_t)(kb*8 + 2*jj)*outc + n]);
    unsigned hi = f2bf(W[(size_t)(kb*8 + 2*jj+1)*outc + n]);
    pk[jj] = lo | (hi << 16);
  }
  *reinterpret_cast<uint4*>(Wp + (size_t)i*8) = make_uint4(pk[0],pk[1],pk[2],pk[3]);
}

// ---------------- MFMA GEMM: C[N x OUTC] = xform(A[N x 128]) * W ----------------
// XFORM: 0 none, 1 relu(a*scale+shift) (BN), 2 relu(a)
// ABF16: A rows are packed bf16 (64 uints); else fp32
// BF16OUT: write bf16 rows scaled by dinv[row]; else fp32 (+bias if ADD_BIAS)
template<int OUTC, int XFORM, bool ADD_BIAS, bool BF16OUT, bool ABF16>
__global__ __launch_bounds__(256) void k_mgemm(const void* __restrict__ Av,
                                               const unsigned short* __restrict__ Wp,
                                               const float* __restrict__ scale,
                                               const float* __restrict__ shiftv,
                                               const float* __restrict__ bias,
                                               const float* __restrict__ dinv,
                                               void* __restrict__ Cv){
  __shared__ char lds[32768 + OUTC*256];   // As (bf16 swizzled) + Ws (packed)
  char* AsB = lds;
  char* WsB = lds + 32768;
  const int t = threadIdx.x;
  const int row0 = blockIdx.x * 128;

  { // stage packed W (bf16) into LDS
    constexpr int NV = OUTC*16;  // uint4 count
    const uint4* src = reinterpret_cast<const uint4*>(Wp);
    uint4* dst = reinterpret_cast<uint4*>(WsB);
    #pragma unroll
    for (int f = 0; f < NV/256; ++f)
      dst[t + f*256] = src[t + f*256];
  }
  if constexpr (ABF16){ // stage bf16 A: XFORM in fp32, repack
    const uint4* A = (const uint4*)Av;   // 16 uint4 per row
    const int c8 = t & 15;               // fixed per thread: feature chunk
    const int k0 = c8*8;
    float sc[8], sh[8];
    if (XFORM == 1){
      #pragma unroll
      for (int j=0;j<8;++j){ sc[j]=scale[k0+j]; sh[j]=shiftv[k0+j]; }
    }
    #pragma unroll
    for (int g = 0; g < 8; ++g){
      int f = g*256 + t;
      int r = f >> 4;
      int row = row0 + r;
      int rc = row < NN ? row : NN-1;
      uint4 q = A[(size_t)rc*16 + c8];
      float vf[8] = { bflo(q.x),bfhi(q.x),bflo(q.y),bfhi(q.y),
                      bflo(q.z),bfhi(q.z),bflo(q.w),bfhi(q.w) };
      if (XFORM == 1){
        #pragma unroll
        for (int j=0;j<8;++j) vf[j] = fmaxf(fmaf(vf[j], sc[j], sh[j]), 0.f);
      } else if (XFORM == 2){
        #pragma unroll
        for (int j=0;j<8;++j) vf[j] = fmaxf(vf[j], 0.f);
      }
      unsigned pk[4];
      #pragma unroll
      for (int j=0;j<4;++j)
        pk[j] = (unsigned)f2bf(vf[2*j]) | ((unsigned)f2bf(vf[2*j+1]) << 16);
      int boff = (c8*16) ^ ((r & 7) << 4);
      *reinterpret_cast<uint4*>(AsB + r*256 + boff) = make_uint4(pk[0],pk[1],pk[2],pk[3]);
    }
  } else { // stage fp32 A -> bf16
    const float* A = (const float*)Av;
    #pragma unroll
    for (int g = 0; g < 16; ++g){
      int f = g*256 + t;
      int r = f >> 5;
      int c4 = f & 31;
      int row = row0 + r;
      int rc = row < NN ? row : NN-1;
      float4 v = *reinterpret_cast<const float4*>(A + (size_t)rc*HN + c4*4);
      if (XFORM == 2){
        v.x = fmaxf(v.x, 0.f); v.y = fmaxf(v.y, 0.f);
        v.z = fmaxf(v.z, 0.f); v.w = fmaxf(v.w, 0.f);
      }
      unsigned p0 = (unsigned)f2bf(v.x) | ((unsigned)f2bf(v.y) << 16);
      unsigned p1 = (unsigned)f2bf(v.z) | ((unsigned)f2bf(v.w) << 16);
      int boff = (c4*8) ^ ((r & 7) << 4);
      *reinterpret_cast<uint2*>(AsB + r*256 + boff) = make_uint2(p0, p1);
    }
  }
  __syncthreads();

  const int wv = t >> 6;
  const int l  = t & 63;
  const int lm = l & 15;
  const int lk = l >> 4;
  constexpr int NF = OUTC/16;

  f32x4 acc[2][NF];
  #pragma unroll
  for (int mi=0;mi<2;++mi)
    #pragma unroll
    for (int ni=0;ni<NF;++ni) acc[mi][ni] = (f32x4){0.f,0.f,0.f,0.f};

  #pragma unroll
  for (int ks = 0; ks < 4; ++ks){
    bf16x8 af[2];
    #pragma unroll
    for (int mi=0;mi<2;++mi){
      int R = wv*32 + mi*16 + lm;
      int boff = (ks*64 + lk*16) ^ ((R & 7) << 4);
      af[mi] = *reinterpret_cast<const bf16x8*>(AsB + R*256 + boff);
    }
    int kb = ks*4 + lk;
    #pragma unroll
    for (int ni=0;ni<NF;++ni){
      int n = ni*16 + lm;
      bf16x8 bfr = *reinterpret_cast<const bf16x8*>(WsB + (kb*OUTC + n)*16);
      acc[0][ni] = __builtin_amdgcn_mfma_f32_16x16x32_bf16(af[0], bfr, acc[0][ni], 0,0,0);
      acc[1][ni] = __builtin_amdgcn_mfma_f32_16x16x32_bf16(af[1], bfr, acc[1][ni], 0,0,0);
    }
  }

  // epilogue: D frag (mi,ni): row = wv*32+mi*16+lk*4+j, col = ni*16+lm
  #pragma unroll
  for (int mi=0;mi<2;++mi){
    #pragma unroll
    for (int j=0;j<4;++j){
      int grow = row0 + wv*32 + mi*16 + lk*4 + j;
      if (grow >= NN) continue;
      if constexpr (BF16OUT){
        float dr = dinv[grow];
        unsigned short* po = (unsigned short*)Cv + (size_t)grow*OUTC;
        #pragma unroll
        for (int ni=0;ni<NF;++ni)
          po[ni*16 + lm] = f2bf(acc[mi][ni][j] * dr);
      } else {
        float* po = (float*)Cv + (size_t)grow*OUTC;
        #pragma unroll
        for (int ni=0;ni<NF;++ni){
          float v = acc[mi][ni][j];
          if (ADD_BIAS) v += bias[ni*16 + lm];
          po[ni*16 + lm] = v;
        }
      }
    }
  }
}

// ---------------- BN stats over bf16 rows (deterministic two-stage) ----------------
__global__ __launch_bounds__(256) void k_stats(const unsigned* __restrict__ a,
                                               float* __restrict__ ps, float* __restrict__ pq){
  __shared__ float l0[256], l1[256], m0[256], m1[256];
  int c = threadIdx.x & 63;
  int grp = threadIdx.x >> 6;
  float s0=0.f,s1=0.f,q0=0.f,q1=0.f;
  for (int r = blockIdx.x*4 + grp; r < NN; r += SB*4){
    unsigned u = a[(size_t)r*64 + c];
    float v0 = bflo(u), v1 = bfhi(u);
    s0 += v0; s1 += v1; q0 = fmaf(v0,v0,q0); q1 = fmaf(v1,v1,q1);
  }
  l0[threadIdx.x]=s0; l1[threadIdx.x]=s1; m0[threadIdx.x]=q0; m1[threadIdx.x]=q1;
  __syncthreads();
  if (grp==0){
    #pragma unroll
    for (int g=1;g<4;++g){ s0+=l0[g*64+c]; s1+=l1[g*64+c]; q0+=m0[g*64+c]; q1+=m1[g*64+c]; }
    ps[blockIdx.x*128 + 2*c]   = s0; ps[blockIdx.x*128 + 2*c+1] = s1;
    pq[blockIdx.x*128 + 2*c]   = q0; pq[blockIdx.x*128 + 2*c+1] = q1;
  }
}

__global__ __launch_bounds__(128) void k_bnfinal(const float* __restrict__ ps, const float* __restrict__ pq,
                                                 const float* __restrict__ gamma, const float* __restrict__ beta,
                                                 float* __restrict__ scale, float* __restrict__ shiftv){
  int c = threadIdx.x;
  float s=0.f, q=0.f;
  for (int b=0;b<SB;b++){ s += ps[b*128+c]; q += pq[b*128+c]; }
  float mean = s * (1.0f/NN);
  float var  = q * (1.0f/NN) - mean*mean;
  float inv  = rsqrtf(var + 1e-5f);
  float sc = gamma[c]*inv;
  scale[c]  = sc;
  shiftv[c] = beta[c] - mean*sc;
}

// ---------------- launch ----------------
extern "C" void kernel_launch(void* const* d_in, const int* in_sizes, int n_in,
                              void* d_out, int out_size, void* d_ws, size_t ws_size,
                              hipStream_t stream) {
  const float* x      = (const float*)d_in[0];
  const int*   ei     = (const int*)d_in[1];
  const int*   rows   = ei;
  const int*   cols   = ei + EE;
  const float* W1     = (const float*)d_in[2];
  const float* b1     = (const float*)d_in[3];
  const float* gamma1 = (const float*)d_in[4];
  const float* beta1  = (const float*)d_in[5];
  const float* W2     = (const float*)d_in[6];
  const float* b2     = (const float*)d_in[7];
  const float* W3     = (const float*)d_in[8];
  const float* b3     = (const float*)d_in[9];
  float* out = (float*)d_out;

  char* w = (char*)d_ws;
  float* buf0      = (float*)w; w += (size_t)NN*HN*4;   // bf16 h (aliased) / ebuf
  float* buf1      = (float*)w; w += (size_t)NN*HN*4;   // bf16 agg output
  int*   csr_col   = (int*)w;   w += (size_t)EE*4;
  int*   row_start = (int*)w;   w += (size_t)NN*4;
  int*   cnt       = (int*)w;   w += (size_t)NN*4;
  float* dinv      = (float*)w; w += (size_t)NN*4;
  float* ps        = (float*)w; w += (size_t)SB*128*4;
  float* pq        = (float*)w; w += (size_t)SB*128*4;
  float* scale     = (float*)w; w += 1024;
  float* shiftv    = (float*)w; w += 1024;
  int*   bcnt      = (int*)w;   w += 1024;
  int*   bbase     = (int*)w;   w += 1024;
  int*   bcur      = (int*)w;   w += 1024;
  unsigned short* Wp1 = (unsigned short*)w; w += 128*128*2;
  unsigned short* Wp2 = (unsigned short*)w; w += 128*128*2;
  unsigned short* Wp3 = (unsigned short*)w; w += 128*64*2;
  uint2*    ebuf  = (uint2*)buf0;
  unsigned* hbf   = (unsigned*)buf0;   // bf16 h rows (64 uints/row)
  unsigned* abf   = (unsigned*)buf1;   // bf16 agg rows

  (void)hipMemsetAsync(bcnt, 0, NBUCK*4, stream);

  const int CB = (EE + CH - 1)/CH, GB = (NN+127)/128, AB = NN/4;

  k_packW3<<<20, 256, 0, stream>>>(W1, W2, W3, Wp1, Wp2, Wp3);

  k_hist  <<<CB, 256, 0, stream>>>(rows, bcnt);
  k_bscan <<<1, 64, 0, stream>>>(bcnt, bbase, bcur);
  k_bucket<<<CB, 256, 0, stream>>>(rows, cols, bcur, ebuf);
  k_build <<<NBUCK, 256, 0, stream>>>(ebuf, bbase, bcnt, row_start, cnt, dinv, csr_col);

  // layer 1: h1' = bf16((x@W1)*dinv), agg -> abf (bf16, +b1)
  k_mgemm<128,0,false,true,false><<<GB, 256, 0, stream>>>(x, Wp1, nullptr, nullptr, nullptr, dinv, hbf);
  k_agg<true><<<AB, 256, 0, stream>>>(hbf, row_start, cnt, csr_col, dinv, b1, abf);
  k_stats<<<SB, 256, 0, stream>>>(abf, ps, pq);
  k_bnfinal<<<1, 128, 0, stream>>>(ps, pq, gamma1, beta1, scale, shiftv);

  // layer 2: BN+relu fused into staging (bf16 A); h2' bf16
  k_mgemm<128,1,false,true,true><<<GB, 256, 0, stream>>>(abf, Wp2, scale, shiftv, nullptr, dinv, hbf);
  k_agg<true><<<AB, 256, 0, stream>>>(hbf, row_start, cnt, csr_col, dinv, b2, abf);

  // layer 3: relu fused into staging (bf16 A), bias on output, fp32 out
  k_mgemm<64,2,true,false,true><<<GB, 256, 0, stream>>>(abf, Wp3, nullptr, nullptr, b3, nullptr, out);
}

// Round 7
// 274.119 us; speedup vs baseline: 1.0002x; 1.0002x over previous
//
#include <hip/hip_runtime.h>

#define NN 100000
#define EE 1600000
#define HN 128
#define OO 64
#define SB 256     // stats blocks
#define NBUCK 196  // ceil(NN/512), bucket = row >> 9
#define CH 4096    // edges per bucketing chunk

typedef __attribute__((ext_vector_type(8))) short bf16x8;
typedef __attribute__((ext_vector_type(4))) float f32x4;

__device__ __forceinline__ unsigned short f2bf(float f){ // RNE bf16
  unsigned u = __float_as_uint(f);
  return (unsigned short)((u + 0x7FFFu + ((u >> 16) & 1u)) >> 16);
}
__device__ __forceinline__ float bflo(unsigned u){ return __uint_as_float(u << 16); }
__device__ __forceinline__ float bfhi(unsigned u){ return __uint_as_float(u & 0xFFFF0000u); }

// ---------------- pass 0: bucket histogram + weight pack (fused) ----------------
__global__ __launch_bounds__(256) void k_histpack(const int* __restrict__ rows, int* __restrict__ bcnt,
                                                  const float* __restrict__ W1, const float* __restrict__ W2,
                                                  const float* __restrict__ W3,
                                                  unsigned short* __restrict__ Wp1, unsigned short* __restrict__ Wp2,
                                                  unsigned short* __restrict__ Wp3){
  __shared__ int h[NBUCK];
  for (int i = threadIdx.x; i < NBUCK; i += 256) h[i] = 0;
  __syncthreads();
  int base = blockIdx.x * CH;
  for (int j = threadIdx.x; j < CH; j += 256){
    int e = base + j;
    if (e < EE) atomicAdd(&h[rows[e] >> 9], 1);
  }
  __syncthreads();
  for (int i = threadIdx.x; i < NBUCK; i += 256){
    int v = h[i];
    if (v) atomicAdd(&bcnt[i], v);
  }
  // weight pack on the first 20 blocks
  int b = blockIdx.x;
  if (b < 20){
    const float* W; unsigned short* Wp; int outc, i0;
    if (b < 8)      { W=W1; Wp=Wp1; outc=128; i0 = b*256; }
    else if (b < 16){ W=W2; Wp=Wp2; outc=128; i0 = (b-8)*256; }
    else            { W=W3; Wp=Wp3; outc=64;  i0 = (b-16)*256; }
    int i = i0 + threadIdx.x;
    if (i < 16*outc){
      int kb = i / outc, n = i - kb*outc;
      unsigned pk[4];
      #pragma unroll
      for (int jj = 0; jj < 4; ++jj){
        unsigned lo = f2bf(W[(size_t)(kb*8 + 2*jj)*outc + n]);
        unsigned hi = f2bf(W[(size_t)(kb*8 + 2*jj+1)*outc + n]);
        pk[jj] = lo | (hi << 16);
      }
      *reinterpret_cast<uint4*>(Wp + (size_t)i*8) = make_uint4(pk[0],pk[1],pk[2],pk[3]);
    }
  }
}

__global__ __launch_bounds__(64) void k_bscan(const int* __restrict__ bcnt,
                                              int* __restrict__ bbase, int* __restrict__ bcur){
  int lane = threadIdx.x;
  int run = 0;
  for (int c = 0; c < NBUCK; c += 64){
    int i = c + lane;
    int v = (i < NBUCK) ? bcnt[i] : 0;
    int s = v;
    #pragma unroll
    for (int d = 1; d < 64; d <<= 1){ int u = __shfl_up(s, d); if (lane >= d) s += u; }
    if (i < NBUCK){ bbase[i] = run + s - v; bcur[i] = run + s - v; }
    run += __shfl(s, 63);
  }
}

__global__ __launch_bounds__(256) void k_bucket(const int* __restrict__ rows, const int* __restrict__ cols,
                                                int* __restrict__ bcur, uint2* __restrict__ ebuf){
  __shared__ int bc[NBUCK];
  __shared__ int boff[NBUCK];
  __shared__ int ccur[NBUCK];
  __shared__ int gbase[NBUCK];
  __shared__ uint2 stage[CH];
  const int t = threadIdx.x;
  const int base = blockIdx.x * CH;
  const int nval = min(CH, EE - base);

  for (int i = t; i < NBUCK; i += 256) bc[i] = 0;
  __syncthreads();

  int er[16], ec[16];
  #pragma unroll
  for (int j = 0; j < 16; ++j){
    int i = j*256 + t;
    if (i < nval){
      er[j] = rows[base+i]; ec[j] = cols[base+i];
      atomicAdd(&bc[er[j] >> 9], 1);
    } else er[j] = -1;
  }
  __syncthreads();

  if (t < 64){
    int lane = t, run = 0;
    for (int c = 0; c < NBUCK; c += 64){
      int i = c + lane;
      int v = (i < NBUCK) ? bc[i] : 0;
      int s = v;
      #pragma unroll
      for (int d = 1; d < 64; d <<= 1){ int u = __shfl_up(s, d); if (lane >= d) s += u; }
      if (i < NBUCK) boff[i] = run + s - v;
      run += __shfl(s, 63);
    }
  }
  __syncthreads();
  if (t < NBUCK){
    gbase[t] = bc[t] ? atomicAdd(&bcur[t], bc[t]) : 0;
    ccur[t]  = boff[t];
  }
  __syncthreads();
  #pragma unroll
  for (int j = 0; j < 16; ++j){
    if (er[j] >= 0){
      int b = er[j] >> 9;
      int p = atomicAdd(&ccur[b], 1);
      stage[p] = make_uint2((unsigned)er[j], (unsigned)ec[j]);
    }
  }
  __syncthreads();
  for (int i = t; i < nval; i += 256){
    uint2 e = stage[i];
    int b = (int)(e.x >> 9);
    ebuf[gbase[b] + (i - boff[b])] = e;
  }
}

__global__ __launch_bounds__(256) void k_build(const uint2* __restrict__ ebuf,
                                               const int* __restrict__ bbase, const int* __restrict__ bcnt,
                                               int* __restrict__ row_start, int* __restrict__ cnt,
                                               float* __restrict__ dinv, int* __restrict__ csr_col){
  __shared__ int hist[512];
  __shared__ int cur[512];
  const int b = blockIdx.x;
  const int row0 = b << 9;
  const int nrow = min(512, NN - row0);
  const int ebase = bbase[b];
  const int ne = bcnt[b];
  const int t = threadIdx.x;

  for (int i = t; i < nrow; i += 256) hist[i] = 0;
  __syncthreads();
  for (int i = t; i < ne; i += 256)
    atomicAdd(&hist[(int)ebuf[ebase+i].x - row0], 1);
  __syncthreads();

  if (t < 64){
    int lane = t, run = 0;
    for (int c = 0; c < nrow; c += 64){
      int i = c + lane;
      int v = (i < nrow) ? hist[i] : 0;
      int s = v;
      #pragma unroll
      for (int d = 1; d < 64; d <<= 1){ int u = __shfl_up(s, d); if (lane >= d) s += u; }
      if (i < nrow) cur[i] = run + s - v;
      run += __shfl(s, 63);
    }
  }
  __syncthreads();
  for (int i = t; i < nrow; i += 256){
    int h = hist[i];
    int r = row0 + i;
    cnt[r] = h;
    dinv[r] = rsqrtf((float)(h+1));
    row_start[r] = ebase + cur[i];
    cur[i] += ebase;
  }
  __syncthreads();
  for (int i = t; i < ne; i += 256){
    uint2 e = ebuf[ebase+i];
    int p = atomicAdd(&cur[(int)e.x - row0], 1);
    csr_col[p] = (int)e.y;
  }
}

// ---------------- aggregation over bf16 rows pre-scaled by dinv (R5 form) ----------------
template<bool BF16OUT>
__global__ __launch_bounds__(256) void k_agg(const unsigned* __restrict__ h,
                                             const int* __restrict__ row_start,
                                             const int* __restrict__ cnt,
                                             const int* __restrict__ col,
                                             const float* __restrict__ dinv,
                                             const float* __restrict__ bias,
                                             void* __restrict__ outv){
  int wib  = __builtin_amdgcn_readfirstlane((int)(threadIdx.x >> 6));  // SGPR wave id
  int wid  = blockIdx.x*4 + wib;
  int lane = threadIdx.x & 63;
  if (wid >= NN) return;
  int s = row_start[wid];           // scalar loads (wid uniform)
  int e = s + cnt[wid];
  float dr = dinv[wid];
  const unsigned* hp = h + lane;
  float ax, ay;
  {
    unsigned u = hp[(size_t)wid*64];
    ax = bflo(u); ay = bfhi(u);
  }
  int p = s;
  for (; p+7 < e; p += 8){           // 8 outstanding gathers
    unsigned uu[8];
    #pragma unroll
    for (int j=0;j<8;++j) uu[j] = hp[(size_t)col[p+j]*64];
    #pragma unroll
    for (int j=0;j<8;++j){ ax += bflo(uu[j]); ay += bfhi(uu[j]); }
  }
  for (; p+3 < e; p += 4){
    unsigned uu[4];
    #pragma unroll
    for (int j=0;j<4;++j) uu[j] = hp[(size_t)col[p+j]*64];
    #pragma unroll
    for (int j=0;j<4;++j){ ax += bflo(uu[j]); ay += bfhi(uu[j]); }
  }
  for (; p < e; ++p){
    unsigned u = hp[(size_t)col[p]*64];
    ax += bflo(u); ay += bfhi(u);
  }
  float2 bb = *reinterpret_cast<const float2*>(bias + 2*lane);
  float ox = ax*dr + bb.x, oy = ay*dr + bb.y;
  if constexpr (BF16OUT){
    ((unsigned*)outv)[(size_t)wid*64 + lane] = (unsigned)f2bf(ox) | ((unsigned)f2bf(oy) << 16);
  } else {
    *reinterpret_cast<float2*>((float*)outv + (size_t)wid*HN + 2*lane) = make_float2(ox, oy);
  }
}

// ---------------- MFMA GEMM: C[N x OUTC] = xform(A[N x 128]) * W ----------------
// B-fragments read directly from global Wp (L1/L2-hot); LDS holds only the A tile (32 KB)
// XFORM: 0 none, 1 relu(a*scale+shift) (BN), 2 relu(a)
// ABF16: A rows are packed bf16 (64 uints); else fp32
// BF16OUT: write bf16 rows scaled by dinv[row]; else fp32 (+bias if ADD_BIAS)
template<int OUTC, int XFORM, bool ADD_BIAS, bool BF16OUT, bool ABF16>
__global__ __launch_bounds__(256) void k_mgemm(const void* __restrict__ Av,
                                               const unsigned short* __restrict__ Wp,
                                               const float* __restrict__ scale,
                                               const float* __restrict__ shiftv,
                                               const float* __restrict__ bias,
                                               const float* __restrict__ dinv,
                                               void* __restrict__ Cv){
  __shared__ char AsB[32768];   // 128 rows x 256 B (bf16, XOR-swizzled)
  const int t = threadIdx.x;
  const int row0 = blockIdx.x * 128;

  if constexpr (ABF16){ // stage bf16 A: XFORM in fp32, repack
    const uint4* A = (const uint4*)Av;   // 16 uint4 per row
    const int c8 = t & 15;               // fixed per thread: feature chunk
    const int k0 = c8*8;
    float sc[8], sh[8];
    if (XFORM == 1){
      #pragma unroll
      for (int j=0;j<8;++j){ sc[j]=scale[k0+j]; sh[j]=shiftv[k0+j]; }
    }
    #pragma unroll
    for (int g = 0; g < 8; ++g){
      int f = g*256 + t;
      int r = f >> 4;
      int row = row0 + r;
      int rc = row < NN ? row : NN-1;
      uint4 q = A[(size_t)rc*16 + c8];
      float vf[8] = { bflo(q.x),bfhi(q.x),bflo(q.y),bfhi(q.y),
                      bflo(q.z),bfhi(q.z),bflo(q.w),bfhi(q.w) };
      if (XFORM == 1){
        #pragma unroll
        for (int j=0;j<8;++j) vf[j] = fmaxf(fmaf(vf[j], sc[j], sh[j]), 0.f);
      } else if (XFORM == 2){
        #pragma unroll
        for (int j=0;j<8;++j) vf[j] = fmaxf(vf[j], 0.f);
      }
      unsigned pk[4];
      #pragma unroll
      for (int j=0;j<4;++j)
        pk[j] = (unsigned)f2bf(vf[2*j]) | ((unsigned)f2bf(vf[2*j+1]) << 16);
      int boff = (c8*16) ^ ((r & 7) << 4);
      *reinterpret_cast<uint4*>(AsB + r*256 + boff) = make_uint4(pk[0],pk[1],pk[2],pk[3]);
    }
  } else { // stage fp32 A -> bf16
    const float* A = (const float*)Av;
    #pragma unroll
    for (int g = 0; g < 16; ++g){
      int f = g*256 + t;
      int r = f >> 5;
      int c4 = f & 31;
      int row = row0 + r;
      int rc = row < NN ? row : NN-1;
      float4 v = *reinterpret_cast<const float4*>(A + (size_t)rc*HN + c4*4);
      if (XFORM == 2){
        v.x = fmaxf(v.x, 0.f); v.y = fmaxf(v.y, 0.f);
        v.z = fmaxf(v.z, 0.f); v.w = fmaxf(v.w, 0.f);
      }
      unsigned p0 = (unsigned)f2bf(v.x) | ((unsigned)f2bf(v.y) << 16);
      unsigned p1 = (unsigned)f2bf(v.z) | ((unsigned)f2bf(v.w) << 16);
      int boff = (c4*8) ^ ((r & 7) << 4);
      *reinterpret_cast<uint2*>(AsB + r*256 + boff) = make_uint2(p0, p1);
    }
  }
  __syncthreads();

  const int wv = t >> 6;
  const int l  = t & 63;
  const int lm = l & 15;
  const int lk = l >> 4;
  constexpr int NF = OUTC/16;

  f32x4 acc[2][NF];
  #pragma unroll
  for (int mi=0;mi<2;++mi)
    #pragma unroll
    for (int ni=0;ni<NF;++ni) acc[mi][ni] = (f32x4){0.f,0.f,0.f,0.f};

  const bf16x8* WpV = reinterpret_cast<const bf16x8*>(Wp);

  #pragma unroll
  for (int ks = 0; ks < 4; ++ks){
    bf16x8 af[2];
    #pragma unroll
    for (int mi=0;mi<2;++mi){
      int R = wv*32 + mi*16 + lm;
      int boff = (ks*64 + lk*16) ^ ((R & 7) << 4);
      af[mi] = *reinterpret_cast<const bf16x8*>(AsB + R*256 + boff);
    }
    int kb = ks*4 + lk;
    #pragma unroll
    for (int ni=0;ni<NF;++ni){
      int n = ni*16 + lm;
      bf16x8 bfr = WpV[kb*OUTC + n];         // global, coalesced 256B/quad, L1-hot
      acc[0][ni] = __builtin_amdgcn_mfma_f32_16x16x32_bf16(af[0], bfr, acc[0][ni], 0,0,0);
      acc[1][ni] = __builtin_amdgcn_mfma_f32_16x16x32_bf16(af[1], bfr, acc[1][ni], 0,0,0);
    }
  }

  // epilogue: D frag (mi,ni): row = wv*32+mi*16+lk*4+j, col = ni*16+lm
  #pragma unroll
  for (int mi=0;mi<2;++mi){
    #pragma unroll
    for (int j=0;j<4;++j){
      int grow = row0 + wv*32 + mi*16 + lk*4 + j;
      if (grow >= NN) continue;
      if constexpr (BF16OUT){
        float dr = dinv[grow];
        unsigned short* po = (unsigned short*)Cv + (size_t)grow*OUTC;
        #pragma unroll
        for (int ni=0;ni<NF;++ni)
          po[ni*16 + lm] = f2bf(acc[mi][ni][j] * dr);
      } else {
        float* po = (float*)Cv + (size_t)grow*OUTC;
        #pragma unroll
        for (int ni=0;ni<NF;++ni){
          float v = acc[mi][ni][j];
          if (ADD_BIAS) v += bias[ni*16 + lm];
          po[ni*16 + lm] = v;
        }
      }
    }
  }
}

// ---------------- BN stats over bf16 rows (deterministic two-stage) ----------------
__global__ __launch_bounds__(256) void k_stats(const unsigned* __restrict__ a,
                                               float* __restrict__ ps, float* __restrict__ pq){
  __shared__ float l0[256], l1[256], m0[256], m1[256];
  int c = threadIdx.x & 63;
  int grp = threadIdx.x >> 6;
  float s0=0.f,s1=0.f,q0=0.f,q1=0.f;
  for (int r = blockIdx.x*4 + grp; r < NN; r += SB*4){
    unsigned u = a[(size_t)r*64 + c];
    float v0 = bflo(u), v1 = bfhi(u);
    s0 += v0; s1 += v1; q0 = fmaf(v0,v0,q0); q1 = fmaf(v1,v1,q1);
  }
  l0[threadIdx.x]=s0; l1[threadIdx.x]=s1; m0[threadIdx.x]=q0; m1[threadIdx.x]=q1;
  __syncthreads();
  if (grp==0){
    #pragma unroll
    for (int g=1;g<4;++g){ s0+=l0[g*64+c]; s1+=l1[g*64+c]; q0+=m0[g*64+c]; q1+=m1[g*64+c]; }
    ps[blockIdx.x*128 + 2*c]   = s0; ps[blockIdx.x*128 + 2*c+1] = s1;
    pq[blockIdx.x*128 + 2*c]   = q0; pq[blockIdx.x*128 + 2*c+1] = q1;
  }
}

__global__ __launch_bounds__(128) void k_bnfinal(const float* __restrict__ ps, const float* __restrict__ pq,
                                                 const float* __restrict__ gamma, const float* __restrict__ beta,
                                                 float* __restrict__ scale, float* __restrict__ shiftv){
  int c = threadIdx.x;
  float s=0.f, q=0.f;
  for (int b=0;b<SB;b++){ s += ps[b*128+c]; q += pq[b*128+c]; }
  float mean = s * (1.0f/NN);
  float var  = q * (1.0f/NN) - mean*mean;
  float inv  = rsqrtf(var + 1e-5f);
  float sc = gamma[c]*inv;
  scale[c]  = sc;
  shiftv[c] = beta[c] - mean*sc;
}

// ---------------- launch ----------------
extern "C" void kernel_launch(void* const* d_in, const int* in_sizes, int n_in,
                              void* d_out, int out_size, void* d_ws, size_t ws_size,
                              hipStream_t stream) {
  const float* x      = (const float*)d_in[0];
  const int*   ei     = (const int*)d_in[1];
  const int*   rows   = ei;
  const int*   cols   = ei + EE;
  const float* W1     = (const float*)d_in[2];
  const float* b1     = (const float*)d_in[3];
  const float* gamma1 = (const float*)d_in[4];
  const float* beta1  = (const float*)d_in[5];
  const float* W2     = (const float*)d_in[6];
  const float* b2     = (const float*)d_in[7];
  const float* W3     = (const float*)d_in[8];
  const float* b3     = (const float*)d_in[9];
  float* out = (float*)d_out;

  char* w = (char*)d_ws;
  float* buf0      = (float*)w; w += (size_t)NN*HN*4;   // bf16 h (aliased) / ebuf
  float* buf1      = (float*)w; w += (size_t)NN*HN*4;   // bf16 agg output
  int*   csr_col   = (int*)w;   w += (size_t)EE*4;
  int*   row_start = (int*)w;   w += (size_t)NN*4;
  int*   cnt       = (int*)w;   w += (size_t)NN*4;
  float* dinv      = (float*)w; w += (size_t)NN*4;
  float* ps        = (float*)w; w += (size_t)SB*128*4;
  float* pq        = (float*)w; w += (size_t)SB*128*4;
  float* scale     = (float*)w; w += 1024;
  float* shiftv    = (float*)w; w += 1024;
  int*   bcnt      = (int*)w;   w += 1024;
  int*   bbase     = (int*)w;   w += 1024;
  int*   bcur      = (int*)w;   w += 1024;
  unsigned short* Wp1 = (unsigned short*)w; w += 128*128*2;
  unsigned short* Wp2 = (unsigned short*)w; w += 128*128*2;
  unsigned short* Wp3 = (unsigned short*)w; w += 128*64*2;
  uint2*    ebuf  = (uint2*)buf0;
  unsigned* hbf   = (unsigned*)buf0;   // bf16 h rows (64 uints/row)
  unsigned* abf   = (unsigned*)buf1;   // bf16 agg rows

  (void)hipMemsetAsync(bcnt, 0, NBUCK*4, stream);

  const int CB = (EE + CH - 1)/CH, GB = (NN+127)/128, AB = NN/4;

  k_histpack<<<CB, 256, 0, stream>>>(rows, bcnt, W1, W2, W3, Wp1, Wp2, Wp3);
  k_bscan <<<1, 64, 0, stream>>>(bcnt, bbase, bcur);
  k_bucket<<<CB, 256, 0, stream>>>(rows, cols, bcur, ebuf);
  k_build <<<NBUCK, 256, 0, stream>>>(ebuf, bbase, bcnt, row_start, cnt, dinv, csr_col);

  // layer 1: h1' = bf16((x@W1)*dinv), agg -> abf (bf16, +b1)
  k_mgemm<128,0,false,true,false><<<GB, 256, 0, stream>>>(x, Wp1, nullptr, nullptr, nullptr, dinv, hbf);
  k_agg<true><<<AB, 256, 0, stream>>>(hbf, row_start, cnt, csr_col, dinv, b1, abf);
  k_stats<<<SB, 256, 0, stream>>>(abf, ps, pq);
  k_bnfinal<<<1, 128, 0, stream>>>(ps, pq, gamma1, beta1, scale, shiftv);

  // layer 2: BN+relu fused into staging (bf16 A); h2' bf16
  k_mgemm<128,1,false,true,true><<<GB, 256, 0, stream>>>(abf, Wp2, scale, shiftv, nullptr, dinv, hbf);
  k_agg<true><<<AB, 256, 0, stream>>>(hbf, row_start, cnt, csr_col, dinv, b2, abf);

  // layer 3: relu fused into staging (bf16 A), bias on output, fp32 out
  k_mgemm<64,2,true,false,true><<<GB, 256, 0, stream>>>(abf, Wp3, nullptr, nullptr, b3, nullptr, out);
}